// Round 16
// baseline (276.110 us; speedup 1.0000x reference)
//
#include <hip/hip_runtime.h>
#include <hip/hip_bf16.h>
#include <stdint.h>

// Problem constants
#define NB    64
#define LSEQ  510
#define DIN   768
#define L1S   128
#define KS    20
#define OUTF  300
#define NPAD  320                 // padded out-features (5 x 64)
#define EPSL  1e-5f

#define M1    (NB * L1S)          // 8192
#define MK    (NB * KS)           // 1280
#define MT    (M1 + MK)           // 9472

// Output layout (flat, in return order, fp32)
#define OFF_H1    0
#define OFF_SCORE (M1 * OUTF)                 // 2,457,600
#define OFF_HK    (2 * M1 * OUTF)             // 4,915,200
#define OFF_SK    (OFF_HK + MK * OUTF)        // 5,299,200

// ws layout (bytes).  Round-14 finding: ws is ~400 MB (harness poison-fills
// it at 6.7 TB/s ~60us/iter — that fill IS the ~185us residual and is at
// HBM roofline; not controllable).
#define WS_FLAG    0
#define WS_SCORES  64            // float[MT]
#define WS_WBF     81920         // ushort[320*768]  (bf16)
#define WS_POOLED  1048576       // ushort[9472*768] (bf16)
#define WS_HPRE    16777216      // float[9472*320]  (GEMM out, pre-LN)
#define WS_NEEDED  (WS_HPRE + (size_t)MT * NPAD * 4)   // ~28.9 MB

typedef short  short8_t  __attribute__((ext_vector_type(8)));
typedef float  float4v_t __attribute__((ext_vector_type(4)));
typedef unsigned short ushort4_t __attribute__((ext_vector_type(4)));
typedef unsigned short ushort8_t __attribute__((ext_vector_type(8)));

// LDS geometry (fused fallback only)
#define SA_STRIDE 776
#define SC_STRIDE 324
#define LDS_BYTES 41984

__device__ inline bool mask_at(const void* m, int idx, int flag) {
    switch (flag) {
        case 1:  return ((const unsigned char*)m)[idx] != 0;
        case 2:  return ((const float*)m)[idx] != 0.0f;
        case 3:  return ((const unsigned short*)m)[idx] != 0;
        default: return ((const int*)m)[idx] != 0;
    }
}

// ---------------------------------------------------------------------------
// Prep kernel: block 0 detects mask encoding; blocks 1..960 convert W -> bf16.
__global__ __launch_bounds__(256)
void prep_kernel(const unsigned int* __restrict__ p, int* __restrict__ flag,
                 const float* __restrict__ W, unsigned short* __restrict__ Wb) {
    if (blockIdx.x == 0) {
        __shared__ int f_bf16, f_f32, f_other;
        if (threadIdx.x == 0) { f_bf16 = 0; f_f32 = 0; f_other = 0; }
        __syncthreads();
        for (int i = threadIdx.x; i < 2048; i += blockDim.x) {
            unsigned int v = p[i];
            if (v <= 1u) continue;
            if (v == 0x3F803F80u)       atomicOr(&f_bf16, 1);
            else if (v == 0x3F800000u)  atomicOr(&f_f32, 1);
            else                        atomicOr(&f_other, 1);
        }
        __syncthreads();
        if (threadIdx.x == 0) {
            int f = 0;
            if (f_bf16)       f = 3;
            else if (f_f32)   f = 2;
            else if (f_other) f = 1;
            *flag = f;
        }
        return;
    }
    int idx = (blockIdx.x - 1) * 256 + threadIdx.x;   // 960 blocks, exact cover
    if (idx >= NPAD * DIN) return;
    int r = idx / DIN;
    float v = (r < OUTF) ? W[idx] : 0.f;              // idx == r*DIN + c
    __hip_bfloat16 b = __float2bfloat16(v);
    Wb[idx] = *(unsigned short*)&b;
}

// ---------------------------------------------------------------------------
// Span-mean pooling, massively parallel (verified round 14).
// 7104 blocks x 256: one float4-task per thread, 4 predicated loads.
__global__ __launch_bounds__(256)
void pool_kernel(const float* __restrict__ t1, const float* __restrict__ know,
                 const int* __restrict__ s1s, const int* __restrict__ s1e,
                 const int* __restrict__ kss, const int* __restrict__ kse,
                 unsigned short* __restrict__ pooled) {
    const int idx = blockIdx.x * 256 + threadIdx.x;
    const int g  = idx / 192;
    const int c4 = idx - g * 192;
    int s, e;
    const float* src;
    if (g < M1) {
        s = s1s[g]; e = s1e[g];
        src = t1 + (size_t)(g >> 7) * (LSEQ * DIN);
    } else {
        int gg = g - M1;
        s = kss[gg]; e = kse[gg];
        src = know + (size_t)(gg / KS) * (LSEQ * DIN);
    }
    if (s < 0) s = 0;
    if (e > LSEQ) e = LSEQ;
    int len = e - s; if (len < 1) len = 1;

    const float4* p = (const float4*)src + s * 192 + c4;
    const float4 z = {0.f, 0.f, 0.f, 0.f};
    float4 v0 = p[0];
    float4 v1 = z, v2 = z, v3 = z;
    if (len > 1) v1 = p[1 * 192];
    if (len > 2) v2 = p[2 * 192];
    if (len > 3) v3 = p[3 * 192];
    float4 acc;
    acc.x = (v0.x + v1.x) + (v2.x + v3.x);
    acc.y = (v0.y + v1.y) + (v2.y + v3.y);
    acc.z = (v0.z + v1.z) + (v2.z + v3.z);
    acc.w = (v0.w + v1.w) + (v2.w + v3.w);
    for (int r = 4; r < len; ++r) {           // defensive; len<=4 for this data
        float4 v = p[r * 192];
        acc.x += v.x; acc.y += v.y; acc.z += v.z; acc.w += v.w;
    }
    const float inv = 1.0f / (float)len;
    __hip_bfloat16 b0 = __float2bfloat16(acc.x * inv);
    __hip_bfloat16 b1 = __float2bfloat16(acc.y * inv);
    __hip_bfloat16 b2 = __float2bfloat16(acc.z * inv);
    __hip_bfloat16 b3 = __float2bfloat16(acc.w * inv);
    ushort4_t pk;
    pk.x = *(unsigned short*)&b0; pk.y = *(unsigned short*)&b1;
    pk.z = *(unsigned short*)&b2; pk.w = *(unsigned short*)&b3;
    *(ushort4_t*)(pooled + (size_t)g * DIN + c4 * 4) = pk;
}

// ---------------------------------------------------------------------------
// Barrier-free GEMM: 5920 one-wave blocks (16 rows x 32 cols, full K=768).
// No LDS, no __syncthreads — A fragments read directly from pooled (L2/L3
// resident), B from Wb (L2-resident). 23 blocks/CU of independent waves
// replaces 2.3 barrier-locked 10-wave blocks: latency hidden by TLP.
// LN decoupled into ln_kernel (reads hpre) — removes the 320-col coupling
// that forced the 592-block shape.
// Fragment layouts (verified):
//   A: row = lane&15, k = (lane>>4)*8 + j   (8 contiguous bf16)
//   B: col = lane&15, k = (lane>>4)*8 + j
//   D: reg i -> row = (lane>>4)*4 + i, col = lane&15
__global__ __launch_bounds__(64)
void gemm3_kernel(const unsigned short* __restrict__ pooled,
                  const unsigned short* __restrict__ Wb,
                  float* __restrict__ hpre) {
    const int b   = blockIdx.x;           // 0..5919
    const int rb  = b / 10;               // row block  (16 rows)
    const int cgb = b - rb * 10;          // col group  (32 cols)
    const int R0  = rb * 16;
    const int lane = threadIdx.x;
    const int quad = lane >> 4;
    const int l16  = lane & 15;

    const unsigned short* arow = pooled + (size_t)(R0 + l16) * DIN + quad * 8;
    const unsigned short* bb0  = Wb + (size_t)(cgb * 32 + l16) * DIN + quad * 8;
    const unsigned short* bb1  = bb0 + 16 * DIN;

    float4v_t acc0 = {0.f, 0.f, 0.f, 0.f};
    float4v_t acc1 = {0.f, 0.f, 0.f, 0.f};

#pragma unroll 4
    for (int k0 = 0; k0 < DIN; k0 += 32) {
        short8_t a  = *(const short8_t*)(arow + k0);
        short8_t b0 = *(const short8_t*)(bb0 + k0);
        short8_t b1 = *(const short8_t*)(bb1 + k0);
        acc0 = __builtin_amdgcn_mfma_f32_16x16x32_bf16(a, b0, acc0, 0, 0, 0);
        acc1 = __builtin_amdgcn_mfma_f32_16x16x32_bf16(a, b1, acc1, 0, 0, 0);
    }

#pragma unroll
    for (int i = 0; i < 4; ++i) {
        const size_t r = (size_t)(R0 + quad * 4 + i) * NPAD + cgb * 32 + l16;
        hpre[r]      = acc0[i];
        hpre[r + 16] = acc1[i];
    }
}

// ---------------------------------------------------------------------------
// LayerNorm + score: 1184 blocks x 512 (8 waves, one row per wave).
// Verbatim verified epilogue logic, sourced from hpre instead of LDS sC.
__global__ __launch_bounds__(512)
void ln_kernel(const float* __restrict__ hpre,
               const float* __restrict__ bias,
               const float* __restrict__ gamma,
               const float* __restrict__ beta,
               const float* __restrict__ Wsc,
               const float* __restrict__ bsc,
               float* __restrict__ out,
               float* __restrict__ scores) {
    const int wave = threadIdx.x >> 6;
    const int lane = threadIdx.x & 63;
    const int g = blockIdx.x * 8 + wave;      // 1184*8 = 9472, exact
    const float bs0 = bsc[0];

    float tv[5];
    float s = 0.f;
#pragma unroll
    for (int m = 0; m < 5; ++m) {
        int c = lane + 64 * m;
        float v = 0.f;
        if (c < OUTF)
            v = hpre[(size_t)g * NPAD + c] + bias[c];
        tv[m] = v; s += v;
    }
#pragma unroll
    for (int off = 32; off > 0; off >>= 1) s += __shfl_xor(s, off, 64);
    const float mean = s * (1.0f / OUTF);
    float vs = 0.f;
#pragma unroll
    for (int m = 0; m < 5; ++m) {
        int c = lane + 64 * m;
        float d = (c < OUTF) ? (tv[m] - mean) : 0.f;
        vs += d * d;
    }
#pragma unroll
    for (int off = 32; off > 0; off >>= 1) vs += __shfl_xor(vs, off, 64);
    const float rstd = rsqrtf(vs * (1.0f / OUTF) + EPSL);

    const size_t off0 = (g < M1) ? (size_t)g * OUTF
                                 : (size_t)OFF_HK + (size_t)(g - M1) * OUTF;
    float sc = 0.f;
#pragma unroll
    for (int m = 0; m < 5; ++m) {
        int c = lane + 64 * m;
        if (c < OUTF) {
            float h = (tv[m] - mean) * rstd * gamma[c] + beta[c];
            out[off0 + c] = h;
            sc += h * Wsc[c];
        }
    }
#pragma unroll
    for (int off = 32; off > 0; off >>= 1) sc += __shfl_xor(sc, off, 64);
    if (lane == 0) scores[g] = sc + bs0;
}

// ---------------------------------------------------------------------------
// FALLBACK: round-11 fused kernel verbatim (measured 71.3 us, total 260.0).
// Used when ws_size < WS_NEEDED.
__global__ __launch_bounds__(640, 5)
void fused_gemm_kernel(const float* __restrict__ t1,
                       const float* __restrict__ know,
                       const int* __restrict__ s1s, const int* __restrict__ s1e,
                       const int* __restrict__ kss, const int* __restrict__ kse,
                       const unsigned short* __restrict__ Wb,
                       const float* __restrict__ bias,
                       const float* __restrict__ gamma,
                       const float* __restrict__ beta,
                       const float* __restrict__ Wsc,
                       const float* __restrict__ bsc,
                       float* __restrict__ out,
                       float* __restrict__ scores) {
    __shared__ unsigned long long lds_raw[LDS_BYTES / 8];
    unsigned short* sA   = (unsigned short*)lds_raw;
    int*   sSrc = (int*)  ((char*)lds_raw + 16 * 1552);
    int*   sLen = (int*)  ((char*)lds_raw + 16 * 1552 + 64);
    float* sInv = (float*)((char*)lds_raw + 16 * 1552 + 128);

    const int tid = threadIdx.x;
    const int R0  = blockIdx.x * 16;
    const bool isk = (R0 >= M1);

    if (tid < 16) {
        int g = R0 + tid;
        int s, e, n;
        if (!isk) { n = g >> 7;          s = s1s[g];      e = s1e[g]; }
        else      { int gg = g - M1; n = gg / KS; s = kss[gg]; e = kse[gg]; }
        if (s < 0) s = 0;
        if (e > LSEQ) e = LSEQ;
        int len = e - s; if (len < 1) len = 1;
        sSrc[tid] = n * (LSEQ * (DIN / 4)) + s * (DIN / 4);
        sLen[tid] = len;
        sInv[tid] = 1.0f / (float)len;
    }
    __syncthreads();

    const float4* src4 = (const float4*)(isk ? know : t1);
    for (int t = tid; t < 16 * 192; t += 640) {
        int sp = t / 192;
        int c4 = t - sp * 192;
        const float4* p = src4 + sSrc[sp] + c4;
        int len = sLen[sp];
        const float4 z = {0.f, 0.f, 0.f, 0.f};
        float4 v0 = p[0];
        float4 v1 = z, v2 = z, v3 = z;
        if (len > 1) v1 = p[1 * 192];
        if (len > 2) v2 = p[2 * 192];
        if (len > 3) v3 = p[3 * 192];
        float4 acc;
        acc.x = (v0.x + v1.x) + (v2.x + v3.x);
        acc.y = (v0.y + v1.y) + (v2.y + v3.y);
        acc.z = (v0.z + v1.z) + (v2.z + v3.z);
        acc.w = (v0.w + v1.w) + (v2.w + v3.w);
        for (int r = 4; r < len; ++r) {
            float4 v = p[r * 192];
            acc.x += v.x; acc.y += v.y; acc.z += v.z; acc.w += v.w;
        }
        float inv = sInv[sp];
        __hip_bfloat16 b0 = __float2bfloat16(acc.x * inv);
        __hip_bfloat16 b1 = __float2bfloat16(acc.y * inv);
        __hip_bfloat16 b2 = __float2bfloat16(acc.z * inv);
        __hip_bfloat16 b3 = __float2bfloat16(acc.w * inv);
        ushort4_t pk;
        pk.x = *(unsigned short*)&b0; pk.y = *(unsigned short*)&b1;
        pk.z = *(unsigned short*)&b2; pk.w = *(unsigned short*)&b3;
        *(ushort4_t*)(sA + sp * SA_STRIDE + c4 * 4) = pk;
    }
    __syncthreads();

    const int wave = tid >> 6;
    const int lane = tid & 63;
    const int quad = lane >> 4;
    const int l16  = lane & 15;
    const int cg   = wave % 5;
    const int kh   = wave / 5;

    const unsigned short* sArow = sA + l16 * SA_STRIDE + quad * 8 + kh * 384;
    const unsigned short* bb = Wb + (size_t)(cg * 64 + l16) * DIN + quad * 8 + kh * 384;

    float4v_t acc0 = {0.f, 0.f, 0.f, 0.f};
    float4v_t acc1 = {0.f, 0.f, 0.f, 0.f};
    float4v_t acc2 = {0.f, 0.f, 0.f, 0.f};
    float4v_t acc3 = {0.f, 0.f, 0.f, 0.f};

#pragma unroll 4
    for (int k0 = 0; k0 < 384; k0 += 32) {
        short8_t a  = *(const short8_t*)(sArow + k0);
        short8_t b0 = *(const short8_t*)(bb + 0 * 16 * DIN + k0);
        short8_t b1 = *(const short8_t*)(bb + 1 * 16 * DIN + k0);
        short8_t b2 = *(const short8_t*)(bb + 2 * 16 * DIN + k0);
        short8_t b3 = *(const short8_t*)(bb + 3 * 16 * DIN + k0);
        acc0 = __builtin_amdgcn_mfma_f32_16x16x32_bf16(a, b0, acc0, 0, 0, 0);
        acc1 = __builtin_amdgcn_mfma_f32_16x16x32_bf16(a, b1, acc1, 0, 0, 0);
        acc2 = __builtin_amdgcn_mfma_f32_16x16x32_bf16(a, b2, acc2, 0, 0, 0);
        acc3 = __builtin_amdgcn_mfma_f32_16x16x32_bf16(a, b3, acc3, 0, 0, 0);
    }

    __syncthreads();
    float* sC = (float*)lds_raw;
#pragma unroll
    for (int i = 0; i < 4; ++i) {
        int r = (kh * 16 + quad * 4 + i) * SC_STRIDE + cg * 64 + l16;
        sC[r +  0] = acc0[i];
        sC[r + 16] = acc1[i];
        sC[r + 32] = acc2[i];
        sC[r + 48] = acc3[i];
    }
    __syncthreads();

    if (wave < 8) {
        const float bs0 = bsc[0];
#pragma unroll
        for (int rr = 0; rr < 2; ++rr) {
            const int r = wave * 2 + rr;
            const int g = R0 + r;
            float tv[5];
            float s = 0.f;
#pragma unroll
            for (int m = 0; m < 5; ++m) {
                int c = lane + 64 * m;
                float v = 0.f;
                if (c < OUTF)
                    v = sC[r * SC_STRIDE + c] + sC[(16 + r) * SC_STRIDE + c] + bias[c];
                tv[m] = v; s += v;
            }
#pragma unroll
            for (int off = 32; off > 0; off >>= 1) s += __shfl_xor(s, off, 64);
            const float mean = s * (1.0f / OUTF);
            float vs = 0.f;
#pragma unroll
            for (int m = 0; m < 5; ++m) {
                int c = lane + 64 * m;
                float d = (c < OUTF) ? (tv[m] - mean) : 0.f;
                vs += d * d;
            }
#pragma unroll
            for (int off = 32; off > 0; off >>= 1) vs += __shfl_xor(vs, off, 64);
            const float rstd = rsqrtf(vs * (1.0f / OUTF) + EPSL);

            const size_t off0 = isk ? (size_t)OFF_HK + (size_t)(g - M1) * OUTF
                                    : (size_t)g * OUTF;
            float sc = 0.f;
#pragma unroll
            for (int m = 0; m < 5; ++m) {
                int c = lane + 64 * m;
                if (c < OUTF) {
                    float h = (tv[m] - mean) * rstd * gamma[c] + beta[c];
                    out[off0 + c] = h;
                    sc += h * Wsc[c];
                }
            }
#pragma unroll
            for (int off = 32; off > 0; off >>= 1) sc += __shfl_xor(sc, off, 64);
            if (lane == 0) scores[g] = sc + bs0;
        }
    }
}

// ---------------------------------------------------------------------------
// Merged masked-softmax + broadcast (unchanged, verified).
__global__ __launch_bounds__(128)
void softmax_bcast_kernel(const float* __restrict__ scores,
                          const void* __restrict__ m1,
                          const void* __restrict__ mk,
                          const int* __restrict__ flagp,
                          float* __restrict__ out) {
    const int flag = *flagp;
    const int b = blockIdx.x;
    const int tid = threadIdx.x;
    const int lane = tid & 63;

    if (b < NB * 5) {
        __shared__ float sprob[L1S];
        const int n = b / 5;
        const int chunk = b - n * 5;
        if (tid < 64) {
            float v0 = scores[n * L1S + lane];
            float v1 = scores[n * L1S + lane + 64];
            if (mask_at(m1, n * L1S + lane, flag))      v0 = -INFINITY;
            if (mask_at(m1, n * L1S + lane + 64, flag)) v1 = -INFINITY;
            float mx = fmaxf(v0, v1);
#pragma unroll
            for (int off = 32; off > 0; off >>= 1) mx = fmaxf(mx, __shfl_xor(mx, off, 64));
            float e0 = __expf(v0 - mx);
            float e1 = __expf(v1 - mx);
            float s = e0 + e1;
#pragma unroll
            for (int off = 32; off > 0; off >>= 1) s += __shfl_xor(s, off, 64);
            float inv = 1.0f / s;
            sprob[lane]      = e0 * inv;
            sprob[lane + 64] = e1 * inv;
        }
        __syncthreads();
        float* dst = out + (size_t)OFF_SCORE + (size_t)n * (L1S * OUTF);
        const int cbase = chunk * 7680;
#pragma unroll
        for (int i = 0; i < 15; ++i) {
            int e0i = cbase + (i * 128 + tid) * 4;
            float4 v;
            v.x = sprob[(e0i + 0) / OUTF];
            v.y = sprob[(e0i + 1) / OUTF];
            v.z = sprob[(e0i + 2) / OUTF];
            v.w = sprob[(e0i + 3) / OUTF];
            *(float4*)(dst + e0i) = v;
        }
    } else {
        const int n = (b - NB * 5) * 2 + (tid >> 6);
        float v = -INFINITY;
        if (lane < KS) {
            v = scores[M1 + n * KS + lane];
            if (mask_at(mk, n * KS + lane, flag)) v = -INFINITY;
        }
        float mx = v;
#pragma unroll
        for (int off = 32; off > 0; off >>= 1) mx = fmaxf(mx, __shfl_xor(mx, off, 64));
        float e = (lane < KS) ? __expf(v - mx) : 0.f;
        float s = e;
#pragma unroll
        for (int off = 32; off > 0; off >>= 1) s += __shfl_xor(s, off, 64);
        if (lane < KS) out[(size_t)OFF_SK + n * KS + lane] = e / s;
    }
}

// ---------------------------------------------------------------------------
extern "C" void kernel_launch(void* const* d_in, const int* in_sizes, int n_in,
                              void* d_out, int out_size, void* d_ws, size_t ws_size,
                              hipStream_t stream) {
    const float* t1   = (const float*)d_in[0];
    const float* know = (const float*)d_in[1];
    const int* s1s = (const int*)d_in[2];
    const int* s1e = (const int*)d_in[3];
    const void* m1 = d_in[4];
    const int* kss = (const int*)d_in[5];
    const int* kse = (const int*)d_in[6];
    const void* mk = d_in[7];
    const float* Wl  = (const float*)d_in[8];
    const float* bl  = (const float*)d_in[9];
    const float* gm  = (const float*)d_in[10];
    const float* bt  = (const float*)d_in[11];
    const float* Wsc = (const float*)d_in[12];
    const float* bsc = (const float*)d_in[13];
    float* out = (float*)d_out;

    char* ws = (char*)d_ws;
    int*            flag   = (int*)(ws + WS_FLAG);
    float*          scores = (float*)(ws + WS_SCORES);
    unsigned short* Wb     = (unsigned short*)(ws + WS_WBF);
    unsigned short* pooled = (unsigned short*)(ws + WS_POOLED);
    float*          hpre   = (float*)(ws + WS_HPRE);

    prep_kernel<<<1 + (NPAD * DIN + 255) / 256, 256, 0, stream>>>(
        (const unsigned int*)m1, flag, Wl, Wb);

    if (ws_size >= WS_NEEDED) {
        pool_kernel<<<(MT * 192) / 256, 256, 0, stream>>>(t1, know, s1s, s1e,
                                                          kss, kse, pooled);
        gemm3_kernel<<<(MT / 16) * (NPAD / 32), 64, 0, stream>>>(pooled, Wb, hpre);
        ln_kernel<<<MT / 8, 512, 0, stream>>>(hpre, bl, gm, bt, Wsc, bsc,
                                              out, scores);
    } else {
        fused_gemm_kernel<<<MT / 16, 640, 0, stream>>>(t1, know, s1s, s1e,
                                                       kss, kse, Wb, bl, gm,
                                                       bt, Wsc, bsc, out, scores);
    }
    softmax_bcast_kernel<<<NB * 5 + NB / 2, 128, 0, stream>>>(scores, m1, mk,
                                                              flag, out);
}

// Round 17
// 259.853 us; speedup vs baseline: 1.0626x; 1.0626x over previous
//
#include <hip/hip_runtime.h>
#include <hip/hip_bf16.h>
#include <stdint.h>

// Problem constants
#define NB    64
#define LSEQ  510
#define DIN   768
#define L1S   128
#define KS    20
#define OUTF  300
#define NPAD  320                 // padded out-features (5 x 64)
#define EPSL  1e-5f

#define M1    (NB * L1S)          // 8192
#define MK    (NB * KS)           // 1280
#define MT    (M1 + MK)           // 9472

// Output layout (flat, in return order, fp32)
#define OFF_H1    0
#define OFF_SCORE (M1 * OUTF)                 // 2,457,600
#define OFF_HK    (2 * M1 * OUTF)             // 4,915,200
#define OFF_SK    (OFF_HK + MK * OUTF)        // 5,299,200

// ws layout (bytes)
#define WS_FLAG    0
#define WS_SCORES  64            // float[MT]
#define WS_WBF     81920         // ushort[320*768]  (bf16)

typedef short  short8_t  __attribute__((ext_vector_type(8)));
typedef float  float4v_t __attribute__((ext_vector_type(4)));
typedef unsigned short ushort4_t __attribute__((ext_vector_type(4)));

// LDS geometry (round-3/11 measured structure, best measured: 71.3 us fused,
// 260.0 us total).  Session ranking of structures (all measured):
//   fused 260.0 < pool+gemm split 268.6 < pool+gemm3+ln split 276.1
// The ~75 us kernel cost is conserved across structures — it rides with the
// ragged span-gather traffic (~43 MB at ~590 GB/s achieved), not with the
// barrier schedule. Harness poison-fills (~180 us/iter at 84% HBM peak) are
// the remaining total and are not controllable.
#define SA_STRIDE 776            // shorts per A row (768 + 8 pad); 1552 B, 16B-aligned
#define SC_STRIDE 324            // floats per C row (320 + 4 pad)
#define LDS_BYTES 41984          // max( 16*1552 + span meta , 2*16*324*4 = 41472 )

__device__ inline bool mask_at(const void* m, int idx, int flag) {
    switch (flag) {
        case 1:  return ((const unsigned char*)m)[idx] != 0;
        case 2:  return ((const float*)m)[idx] != 0.0f;
        case 3:  return ((const unsigned short*)m)[idx] != 0;
        default: return ((const int*)m)[idx] != 0;
    }
}

// ---------------------------------------------------------------------------
// Prep kernel: block 0 detects mask encoding; blocks 1..960 convert W -> bf16.
__global__ __launch_bounds__(256)
void prep_kernel(const unsigned int* __restrict__ p, int* __restrict__ flag,
                 const float* __restrict__ W, unsigned short* __restrict__ Wb) {
    if (blockIdx.x == 0) {
        __shared__ int f_bf16, f_f32, f_other;
        if (threadIdx.x == 0) { f_bf16 = 0; f_f32 = 0; f_other = 0; }
        __syncthreads();
        for (int i = threadIdx.x; i < 2048; i += blockDim.x) {
            unsigned int v = p[i];
            if (v <= 1u) continue;
            if (v == 0x3F803F80u)       atomicOr(&f_bf16, 1);
            else if (v == 0x3F800000u)  atomicOr(&f_f32, 1);
            else                        atomicOr(&f_other, 1);
        }
        __syncthreads();
        if (threadIdx.x == 0) {
            int f = 0;
            if (f_bf16)       f = 3;
            else if (f_f32)   f = 2;
            else if (f_other) f = 1;
            *flag = f;
        }
        return;
    }
    int idx = (blockIdx.x - 1) * 256 + threadIdx.x;   // 960 blocks, exact cover
    if (idx >= NPAD * DIN) return;
    int r = idx / DIN;
    float v = (r < OUTF) ? W[idx] : 0.f;              // idx == r*DIN + c
    __hip_bfloat16 b = __float2bfloat16(v);
    Wb[idx] = *(unsigned short*)&b;
}

// ---------------------------------------------------------------------------
// Fused: span-mean pool (global fp32 -> LDS bf16) + MFMA GEMM (split-K x2)
// + bias/LayerNorm/score epilogue.  BEST MEASURED (71.3 us, round 11).
// 640 threads = 10 waves, 16 rows x 320 cols; wave w: col group cg=w%5,
// K half kh=w/5; sC LDS round-trip for the cross-kh reduction.
// Measured-worse alternatives (do not re-attempt without new evidence):
//   - no-split-K 10x32-col variant: 82.9 us spill-free (rounds 5/6/10)
//   - pool/gemm kernel fission: +8.6 us total (round 14)
//   - barrier-free 1-wave gemm + separate LN: +16.1 us total (round 16)
// Pooling: 4-wide masked unroll (span len <= 4 by construction) — the
// serial dependent-load chain becomes 4 independent predicated loads.
// __launch_bounds__ MEASURED LAW: VGPR cap = 256/waves_per_eu
//   (640,8)->32 spills 73MB; (640,5)->48 ok (this kernel uses 24).
__global__ __launch_bounds__(640, 5)
void fused_gemm_kernel(const float* __restrict__ t1,
                       const float* __restrict__ know,
                       const int* __restrict__ s1s, const int* __restrict__ s1e,
                       const int* __restrict__ kss, const int* __restrict__ kse,
                       const unsigned short* __restrict__ Wb,   // bf16 [320][768]
                       const float* __restrict__ bias,
                       const float* __restrict__ gamma,
                       const float* __restrict__ beta,
                       const float* __restrict__ Wsc,
                       const float* __restrict__ bsc,
                       float* __restrict__ out,
                       float* __restrict__ scores) {
    __shared__ unsigned long long lds_raw[LDS_BYTES / 8];
    unsigned short* sA   = (unsigned short*)lds_raw;            // [16][776]
    int*   sSrc = (int*)  ((char*)lds_raw + 16 * 1552);         // [16] float4 idx
    int*   sLen = (int*)  ((char*)lds_raw + 16 * 1552 + 64);    // [16]
    float* sInv = (float*)((char*)lds_raw + 16 * 1552 + 128);   // [16]

    const int tid = threadIdx.x;
    const int R0  = blockIdx.x * 16;
    const bool isk = (R0 >= M1);                 // uniform per block (512/80 split)

    // ---- span metadata ----
    if (tid < 16) {
        int g = R0 + tid;
        int s, e, n;
        if (!isk) { n = g >> 7;          s = s1s[g];      e = s1e[g]; }
        else      { int gg = g - M1; n = gg / KS; s = kss[gg]; e = kse[gg]; }
        if (s < 0) s = 0;
        if (e > LSEQ) e = LSEQ;
        int len = e - s; if (len < 1) len = 1;
        sSrc[tid] = n * (LSEQ * (DIN / 4)) + s * (DIN / 4);
        sLen[tid] = len;
        sInv[tid] = 1.0f / (float)len;
    }
    __syncthreads();

    // ---- pooling: 16 spans x 192 float4-cols = 3072 tasks.
    //      4-wide masked unroll: all loads of a task issue independently. ----
    const float4* src4 = (const float4*)(isk ? know : t1);
    for (int t = tid; t < 16 * 192; t += 640) {
        int sp = t / 192;
        int c4 = t - sp * 192;
        const float4* p = src4 + sSrc[sp] + c4;
        int len = sLen[sp];
        const float4 z = {0.f, 0.f, 0.f, 0.f};
        float4 v0 = p[0];
        float4 v1 = z, v2 = z, v3 = z;
        if (len > 1) v1 = p[1 * 192];
        if (len > 2) v2 = p[2 * 192];
        if (len > 3) v3 = p[3 * 192];
        float4 acc;
        acc.x = (v0.x + v1.x) + (v2.x + v3.x);
        acc.y = (v0.y + v1.y) + (v2.y + v3.y);
        acc.z = (v0.z + v1.z) + (v2.z + v3.z);
        acc.w = (v0.w + v1.w) + (v2.w + v3.w);
        for (int r = 4; r < len; ++r) {       // defensive; len<=4 for this data
            float4 v = p[r * 192];
            acc.x += v.x; acc.y += v.y; acc.z += v.z; acc.w += v.w;
        }
        float inv = sInv[sp];
        __hip_bfloat16 b0 = __float2bfloat16(acc.x * inv);
        __hip_bfloat16 b1 = __float2bfloat16(acc.y * inv);
        __hip_bfloat16 b2 = __float2bfloat16(acc.z * inv);
        __hip_bfloat16 b3 = __float2bfloat16(acc.w * inv);
        ushort4_t pk;
        pk.x = *(unsigned short*)&b0; pk.y = *(unsigned short*)&b1;
        pk.z = *(unsigned short*)&b2; pk.w = *(unsigned short*)&b3;
        *(ushort4_t*)(sA + sp * SA_STRIDE + c4 * 4) = pk;
    }
    __syncthreads();

    // ---- MFMA GEMM, split-K ----
    const int wave = tid >> 6;            // 0..9
    const int lane = tid & 63;
    const int quad = lane >> 4;
    const int l16  = lane & 15;
    const int cg   = wave % 5;            // col group: cols [64cg, 64cg+64)
    const int kh   = wave / 5;            // K half: [384kh, 384kh+384)

    const unsigned short* sArow = sA + l16 * SA_STRIDE + quad * 8 + kh * 384;
    const unsigned short* bb = Wb + (size_t)(cg * 64 + l16) * DIN + quad * 8 + kh * 384;

    float4v_t acc0 = {0.f, 0.f, 0.f, 0.f};
    float4v_t acc1 = {0.f, 0.f, 0.f, 0.f};
    float4v_t acc2 = {0.f, 0.f, 0.f, 0.f};
    float4v_t acc3 = {0.f, 0.f, 0.f, 0.f};

#pragma unroll 4
    for (int k0 = 0; k0 < 384; k0 += 32) {
        short8_t a  = *(const short8_t*)(sArow + k0);
        short8_t b0 = *(const short8_t*)(bb + 0 * 16 * DIN + k0);
        short8_t b1 = *(const short8_t*)(bb + 1 * 16 * DIN + k0);
        short8_t b2 = *(const short8_t*)(bb + 2 * 16 * DIN + k0);
        short8_t b3 = *(const short8_t*)(bb + 3 * 16 * DIN + k0);
        acc0 = __builtin_amdgcn_mfma_f32_16x16x32_bf16(a, b0, acc0, 0, 0, 0);
        acc1 = __builtin_amdgcn_mfma_f32_16x16x32_bf16(a, b1, acc1, 0, 0, 0);
        acc2 = __builtin_amdgcn_mfma_f32_16x16x32_bf16(a, b2, acc2, 0, 0, 0);
        acc3 = __builtin_amdgcn_mfma_f32_16x16x32_bf16(a, b3, acc3, 0, 0, 0);
    }

    // ---- dump partials (sC aliases sA; all ds_reads of sA are complete) ----
    __syncthreads();
    float* sC = (float*)lds_raw;          // [2][16][SC_STRIDE]
#pragma unroll
    for (int i = 0; i < 4; ++i) {
        int r = (kh * 16 + quad * 4 + i) * SC_STRIDE + cg * 64 + l16;
        sC[r +  0] = acc0[i];
        sC[r + 16] = acc1[i];
        sC[r + 32] = acc2[i];
        sC[r + 48] = acc3[i];
    }
    __syncthreads();

    // ---- epilogue: bias + LayerNorm + score.  Waves 0..7, 2 rows each ----
    if (wave < 8) {
        const float bs0 = bsc[0];
#pragma unroll
        for (int rr = 0; rr < 2; ++rr) {
            const int r = wave * 2 + rr;
            const int g = R0 + r;
            float tv[5];
            float s = 0.f;
#pragma unroll
            for (int m = 0; m < 5; ++m) {
                int c = lane + 64 * m;
                float v = 0.f;
                if (c < OUTF)
                    v = sC[r * SC_STRIDE + c] + sC[(16 + r) * SC_STRIDE + c] + bias[c];
                tv[m] = v; s += v;
            }
#pragma unroll
            for (int off = 32; off > 0; off >>= 1) s += __shfl_xor(s, off, 64);
            const float mean = s * (1.0f / OUTF);
            float vs = 0.f;
#pragma unroll
            for (int m = 0; m < 5; ++m) {
                int c = lane + 64 * m;
                float d = (c < OUTF) ? (tv[m] - mean) : 0.f;
                vs += d * d;
            }
#pragma unroll
            for (int off = 32; off > 0; off >>= 1) vs += __shfl_xor(vs, off, 64);
            const float rstd = rsqrtf(vs * (1.0f / OUTF) + EPSL);

            const size_t off0 = isk ? (size_t)OFF_HK + (size_t)(g - M1) * OUTF
                                    : (size_t)g * OUTF;
            float sc = 0.f;
#pragma unroll
            for (int m = 0; m < 5; ++m) {
                int c = lane + 64 * m;
                if (c < OUTF) {
                    float h = (tv[m] - mean) * rstd * gamma[c] + beta[c];
                    out[off0 + c] = h;
                    sc += h * Wsc[c];
                }
            }
#pragma unroll
            for (int off = 32; off > 0; off >>= 1) sc += __shfl_xor(sc, off, 64);
            if (lane == 0) scores[g] = sc + bs0;
        }
    }
}

// ---------------------------------------------------------------------------
// Merged masked-softmax + broadcast.  128-thread blocks (2 waves).
// Blocks 0..319: branch1. Block b -> row n = b/5, chunk = b%5. Wave 0
// recomputes row n's softmax (redundant 5x per row; 512 B re-read — noise)
// into LDS, then all 128 threads write 15 float4 each of the broadcast
// score region (exact cover: 5*128*15*4 = 38400 floats per row).
// Blocks 320..351: know softmax. Wave w -> row n=(b-320)*2+w, writes sk.
__global__ __launch_bounds__(128)
void softmax_bcast_kernel(const float* __restrict__ scores,
                          const void* __restrict__ m1,
                          const void* __restrict__ mk,
                          const int* __restrict__ flagp,
                          float* __restrict__ out) {
    const int flag = *flagp;
    const int b = blockIdx.x;
    const int tid = threadIdx.x;
    const int lane = tid & 63;

    if (b < NB * 5) {
        __shared__ float sprob[L1S];
        const int n = b / 5;
        const int chunk = b - n * 5;
        if (tid < 64) {
            float v0 = scores[n * L1S + lane];
            float v1 = scores[n * L1S + lane + 64];
            if (mask_at(m1, n * L1S + lane, flag))      v0 = -INFINITY;
            if (mask_at(m1, n * L1S + lane + 64, flag)) v1 = -INFINITY;
            float mx = fmaxf(v0, v1);
#pragma unroll
            for (int off = 32; off > 0; off >>= 1) mx = fmaxf(mx, __shfl_xor(mx, off, 64));
            float e0 = __expf(v0 - mx);
            float e1 = __expf(v1 - mx);
            float s = e0 + e1;
#pragma unroll
            for (int off = 32; off > 0; off >>= 1) s += __shfl_xor(s, off, 64);
            float inv = 1.0f / s;
            sprob[lane]      = e0 * inv;
            sprob[lane + 64] = e1 * inv;
        }
        __syncthreads();
        // write 1/5 of row n's broadcast region: floats [chunk*7680, +7680)
        float* dst = out + (size_t)OFF_SCORE + (size_t)n * (L1S * OUTF);
        const int cbase = chunk * 7680;
#pragma unroll
        for (int i = 0; i < 15; ++i) {
            int e0i = cbase + (i * 128 + tid) * 4;    // float index in row region
            float4 v;
            v.x = sprob[(e0i + 0) / OUTF];
            v.y = sprob[(e0i + 1) / OUTF];
            v.z = sprob[(e0i + 2) / OUTF];
            v.w = sprob[(e0i + 3) / OUTF];
            *(float4*)(dst + e0i) = v;
        }
    } else {
        const int n = (b - NB * 5) * 2 + (tid >> 6);   // 32 blocks x 2 waves = 64 rows
        float v = -INFINITY;
        if (lane < KS) {
            v = scores[M1 + n * KS + lane];
            if (mask_at(mk, n * KS + lane, flag)) v = -INFINITY;
        }
        float mx = v;
#pragma unroll
        for (int off = 32; off > 0; off >>= 1) mx = fmaxf(mx, __shfl_xor(mx, off, 64));
        float e = (lane < KS) ? __expf(v - mx) : 0.f;
        float s = e;
#pragma unroll
        for (int off = 32; off > 0; off >>= 1) s += __shfl_xor(s, off, 64);
        if (lane < KS) out[(size_t)OFF_SK + n * KS + lane] = e / s;
    }
}

// ---------------------------------------------------------------------------
extern "C" void kernel_launch(void* const* d_in, const int* in_sizes, int n_in,
                              void* d_out, int out_size, void* d_ws, size_t ws_size,
                              hipStream_t stream) {
    const float* t1   = (const float*)d_in[0];
    const float* know = (const float*)d_in[1];
    const int* s1s = (const int*)d_in[2];
    const int* s1e = (const int*)d_in[3];
    const void* m1 = d_in[4];
    const int* kss = (const int*)d_in[5];
    const int* kse = (const int*)d_in[6];
    const void* mk = d_in[7];
    const float* Wl  = (const float*)d_in[8];
    const float* bl  = (const float*)d_in[9];
    const float* gm  = (const float*)d_in[10];
    const float* bt  = (const float*)d_in[11];
    const float* Wsc = (const float*)d_in[12];
    const float* bsc = (const float*)d_in[13];
    float* out = (float*)d_out;

    char* ws = (char*)d_ws;
    int*            flag   = (int*)(ws + WS_FLAG);
    float*          scores = (float*)(ws + WS_SCORES);
    unsigned short* Wb     = (unsigned short*)(ws + WS_WBF);

    prep_kernel<<<1 + (NPAD * DIN + 255) / 256, 256, 0, stream>>>(
        (const unsigned int*)m1, flag, Wl, Wb);
    fused_gemm_kernel<<<MT / 16, 640, 0, stream>>>(t1, know, s1s, s1e, kss, kse,
                                                   Wb, bl, gm, bt, Wsc, bsc,
                                                   out, scores);
    softmax_bcast_kernel<<<NB * 5 + NB / 2, 128, 0, stream>>>(scores, m1, mk,
                                                              flag, out);
}